// Round 5
// baseline (347.318 us; speedup 1.0000x reference)
//
#include <hip/hip_runtime.h>
#include <hip/hip_cooperative_groups.h>
#include <math.h>

namespace cg = cooperative_groups;

#define EPS 1e-8f
#define NN 65536

// ---- fused-kernel ws layout (float offsets) ----
#define F_GATES 0        // 2048
#define F_HNEW  2048     // 512
#define F_ROUT  2560     // 518 (pad 520)
#define F_PMAX  3104     // 512
#define F_PEXP  3616     // 512
#define F_S     4128     // 65536 (P5 aliases first 32768 as PART2)
#define F_PSUM  69664    // 512
#define F_PART  70176    // 512*512 = 262144; end 332320 floats (~1.33 MB)
#define F_PART2 F_S

// ---- fallback (R3) ws layout ----
#define WS_GATES 0
#define WS_HNEW  2048
#define WS_ROUT  2560
#define WS_PMAX  3104    // 2048
#define WS_PEXP  5152    // 2048
#define WS_S     7200    // 65536
#define WS_PSUM  72736   // 256
#define WS_PART  72992   // 256*512

__device__ __forceinline__ float wave_sum(float v) {
    for (int o = 32; o > 0; o >>= 1) v += __shfl_xor(v, o);
    return v;
}
__device__ __forceinline__ float sigm(float x) { return 1.f / (1.f + expf(-x)); }
__device__ __forceinline__ float softplusf_(float x) {
    return x > 20.f ? x : log1pf(expf(x));
}
__device__ __forceinline__ float dot4(float4 a, float4 b) {
    return a.x * b.x + a.y * b.y + a.z * b.z + a.w * b.w;
}
__device__ __forceinline__ float4 ld4(const float* p) { return *(const float4*)p; }

// ============================ fused cooperative ============================
__global__ __launch_bounds__(256, 2) void k_fused(
    const float* __restrict__ x, const float* __restrict__ mem,
    const float* __restrict__ pr, const float* __restrict__ h,
    const float* __restrict__ c, const float* __restrict__ rs,
    const float* __restrict__ W_ih, const float* __restrict__ b_ih,
    const float* __restrict__ W_hh, const float* __restrict__ b_hh,
    const float* __restrict__ W_read, const float* __restrict__ b_read,
    const float* __restrict__ W_out, const float* __restrict__ b_out,
    float* __restrict__ ws, float* __restrict__ out)
{
    cg::grid_group grid = cg::this_grid();
    const int b = blockIdx.x, t = threadIdx.x;
    const int lane = t & 63, wv = t >> 6;

    __shared__ float sh[512];
    __shared__ float sred[8];
    __shared__ float wi_l[130];
    __shared__ float pl[128];
    __shared__ float s_ps[2];
    __shared__ float4 sacc[128];

    // ---- P1: gates (512 blocks x 4 waves = 2048 outputs) ----
    {
        const int o = b * 4 + wv;
        const float* wi = W_ih + (size_t)o * 768;
        const float* wh = W_hh + (size_t)o * 512;
        float acc = dot4(ld4(wi + lane * 4), ld4(x + lane * 4))
                  + dot4(ld4(wi + 256 + lane * 4), ld4(pr + lane * 4))
                  + dot4(ld4(wi + 512 + lane * 4), ld4(pr + 256 + lane * 4))
                  + dot4(ld4(wh + lane * 4), ld4(h + lane * 4))
                  + dot4(ld4(wh + 256 + lane * 4), ld4(h + 256 + lane * 4));
        acc = wave_sum(acc);
        if (lane == 0) ws[F_GATES + o] = acc + b_ih[o] + b_hh[o];
    }
    grid.sync();

    // ---- P2: h_new + r_out ----
    if (b < 130) {
        for (int j = t; j < 512; j += 256) {
            float ig = ws[F_GATES + j];
            float fg = ws[F_GATES + 512 + j];
            float gg = ws[F_GATES + 1024 + j];
            float og = ws[F_GATES + 1536 + j];
            float cn = sigm(fg) * c[j] + sigm(ig) * tanhf(gg);
            float hn = sigm(og) * tanhf(cn);
            sh[j] = hn;
            if (b == 0) ws[F_HNEW + j] = hn;
        }
        __syncthreads();
        const int o = b * 4 + wv;
        if (o < 518) {
            const float* wr = W_read + (size_t)o * 512;
            float acc = dot4(ld4(wr + lane * 4), ld4(sh + lane * 4))
                      + dot4(ld4(wr + 256 + lane * 4), ld4(sh + 256 + lane * 4));
            acc = wave_sum(acc);
            if (lane == 0) ws[F_ROUT + o] = acc + b_read[o];
        }
    }
    grid.sync();

    // ---- P3: cosine scores, 2 rows/wave, dual chains (2048 waves) ----
    {
        const float* key = ws + F_ROUT;
        float4 ka = ld4(key + lane * 4);
        float4 kb = ld4(key + 256 + lane * 4);
        ka.x += EPS; ka.y += EPS; ka.z += EPS; ka.w += EPS;
        kb.x += EPS; kb.y += EPS; kb.z += EPS; kb.w += EPS;
        const float nb_ = fmaxf(sqrtf(wave_sum(dot4(ka, ka) + dot4(kb, kb))), EPS);
        const float beta = softplusf_(key[512]);
        const int gw = b * 4 + wv;  // [0,2048)
        float m = -1e30f, e = 0.f;
        int n = gw;
        float4 va0 = ld4(mem + (size_t)n * 512 + lane * 4);
        float4 vb0 = ld4(mem + (size_t)n * 512 + 256 + lane * 4);
        float4 va1 = ld4(mem + (size_t)(n + 2048) * 512 + lane * 4);
        float4 vb1 = ld4(mem + (size_t)(n + 2048) * 512 + 256 + lane * 4);
        #pragma unroll 2
        for (int i = 0; i < 16; ++i) {
            float4 wa0 = va0, wb0 = vb0, wa1 = va1, wb1 = vb1;
            const int nn2 = n + 4096;
            if (i < 15) {
                va0 = ld4(mem + (size_t)nn2 * 512 + lane * 4);
                vb0 = ld4(mem + (size_t)nn2 * 512 + 256 + lane * 4);
                va1 = ld4(mem + (size_t)(nn2 + 2048) * 512 + lane * 4);
                vb1 = ld4(mem + (size_t)(nn2 + 2048) * 512 + 256 + lane * 4);
            }
            wa0.x += EPS; wa0.y += EPS; wa0.z += EPS; wa0.w += EPS;
            wb0.x += EPS; wb0.y += EPS; wb0.z += EPS; wb0.w += EPS;
            wa1.x += EPS; wa1.y += EPS; wa1.z += EPS; wa1.w += EPS;
            wb1.x += EPS; wb1.y += EPS; wb1.z += EPS; wb1.w += EPS;
            float d0 = dot4(wa0, ka) + dot4(wb0, kb);
            float q0 = dot4(wa0, wa0) + dot4(wb0, wb0);
            float d1 = dot4(wa1, ka) + dot4(wb1, kb);
            float q1 = dot4(wa1, wa1) + dot4(wb1, wb1);
            for (int o = 32; o > 0; o >>= 1) {
                d0 += __shfl_xor(d0, o);
                q0 += __shfl_xor(q0, o);
                d1 += __shfl_xor(d1, o);
                q1 += __shfl_xor(q1, o);
            }
            float sv0 = beta * d0 / (fmaxf(sqrtf(q0), EPS) * nb_);
            float sv1 = beta * d1 / (fmaxf(sqrtf(q1), EPS) * nb_);
            if (lane == 0) {
                ws[F_S + n] = sv0;
                ws[F_S + n + 2048] = sv1;
            }
            float nm = fmaxf(m, fmaxf(sv0, sv1));
            e = e * expf(m - nm) + expf(sv0 - nm) + expf(sv1 - nm);
            m = nm;
            n = nn2;
        }
        if (lane == 0) { sred[wv] = m; sred[4 + wv] = e; }
        __syncthreads();
        if (t == 0) {
            float M = fmaxf(fmaxf(sred[0], sred[1]), fmaxf(sred[2], sred[3]));
            float E = sred[4] * expf(sred[0] - M) + sred[5] * expf(sred[1] - M)
                    + sred[6] * expf(sred[2] - M) + sred[7] * expf(sred[3] - M);
            ws[F_PMAX + b] = M;
            ws[F_PEXP + b] = E;
        }
    }
    grid.sync();

    // ---- P4: stats (redundant per block) + p + column partials (128 rows/block) ----
    {
        float m = -1e30f, e = 0.f;
        for (int i = t; i < 512; i += 256) {
            float bm = ws[F_PMAX + i], be = ws[F_PEXP + i];
            float nm = fmaxf(m, bm);
            e = e * expf(m - nm) + be * expf(bm - nm);
            m = nm;
        }
        for (int o = 32; o > 0; o >>= 1) {
            float om = __shfl_xor(m, o), oe = __shfl_xor(e, o);
            float nm = fmaxf(m, om);
            e = e * expf(m - nm) + oe * expf(om - nm);
            m = nm;
        }
        if (lane == 0) { sred[wv] = m; sred[4 + wv] = e; }
        __syncthreads();
        const float mx = fmaxf(fmaxf(sred[0], sred[1]), fmaxf(sred[2], sred[3]));
        const float Z = sred[4] * expf(sred[0] - mx) + sred[5] * expf(sred[1] - mx)
                      + sred[6] * expf(sred[2] - mx) + sred[7] * expf(sred[3] - mx);
        const float invZ = 1.f / Z;
        const float g = sigm(ws[F_ROUT + 513]);
        float a3 = ws[F_ROUT + 514], b3 = ws[F_ROUT + 515], c3 = ws[F_ROUT + 516];
        float mm = fmaxf(a3, fmaxf(b3, c3));
        float ea = expf(a3 - mm), eb = expf(b3 - mm), ec = expf(c3 - mm);
        float ssum = ea + eb + ec;
        const float s0 = ea / ssum, s1 = eb / ssum, s2 = ec / ssum;
        const float gamma = 1.f + softplusf_(ws[F_ROUT + 517]);

        const int start = b * 128;
        if (t < 130) {
            int idx = (start - 1 + t) & (NN - 1);
            wi_l[t] = g * rs[idx] + (1.f - g) * expf(ws[F_S + idx] - mx) * invZ;
        }
        __syncthreads();
        float ps = 0.f;
        if (t < 128) {
            float wsh = wi_l[t] * s0 + wi_l[t + 1] * s1 + wi_l[t + 2] * s2;
            float pv = powf(wsh, gamma);
            pl[t] = pv;
            ps = pv;
        }
        ps = wave_sum(ps);
        if (t < 128 && lane == 0) s_ps[wv] = ps;
        __syncthreads();
        if (t == 0) ws[F_PSUM + b] = s_ps[0] + s_ps[1];

        const int col = (t & 127) * 4, rh = t >> 7;
        float4 acc = make_float4(0.f, 0.f, 0.f, 0.f);
        const float* basep = mem + (size_t)start * 512 + col;
        #pragma unroll 8
        for (int r = rh; r < 128; r += 2) {
            float w = pl[r];
            float4 v = ld4(basep + (size_t)r * 512);
            acc.x += w * v.x; acc.y += w * v.y; acc.z += w * v.z; acc.w += w * v.w;
        }
        if (rh) sacc[t & 127] = acc;
        __syncthreads();
        if (!rh) {
            float4 a1 = sacc[t & 127];
            acc.x += a1.x; acc.y += a1.y; acc.z += a1.z; acc.w += a1.w;
            *(float4*)(ws + F_PART + (size_t)b * 512 + col) = acc;
        }
    }
    grid.sync();

    // ---- P5: PART2[64][512] = 8-row sums of PART (aliased onto F_S) ----
    if (b < 64) {
        const float* pp = ws + F_PART + (size_t)b * 8 * 512 + t * 2;
        float ax = 0.f, ay = 0.f;
        #pragma unroll
        for (int r = 0; r < 8; ++r) {
            float2 v = *(const float2*)(pp + r * 512);
            ax += v.x; ay += v.y;
        }
        *(float2*)(ws + F_PART2 + (size_t)b * 512 + t * 2) = make_float2(ax, ay);
    }
    grid.sync();

    // ---- P6: Zp + read + out (64 blocks, wave per output) ----
    if (b < 64) {
        float z = 0.f;
        for (int i = t; i < 512; i += 256) z += ws[F_PSUM + i];
        z = wave_sum(z);
        if (lane == 0) sred[wv] = z;
        __syncthreads();
        const float Zp = sred[0] + sred[1] + sred[2] + sred[3];
        const float invZp = 1.f / (Zp + EPS);
        float ax = 0.f, ay = 0.f;
        const float* p2 = ws + F_PART2 + t * 2;
        #pragma unroll 8
        for (int r = 0; r < 64; ++r) {
            float2 v = *(const float2*)(p2 + (size_t)r * 512);
            ax += v.x; ay += v.y;
        }
        __syncthreads();
        sh[2 * t] = ax * invZp;
        sh[2 * t + 1] = ay * invZp;
        __syncthreads();
        const int o = b * 4 + wv;
        const float* wo = W_out + (size_t)o * 1024;
        float acc = dot4(ld4(wo + lane * 4), ld4(ws + F_HNEW + lane * 4))
                  + dot4(ld4(wo + 256 + lane * 4), ld4(ws + F_HNEW + 256 + lane * 4))
                  + dot4(ld4(wo + 512 + lane * 4), ld4(sh + lane * 4))
                  + dot4(ld4(wo + 768 + lane * 4), ld4(sh + 256 + lane * 4));
        acc = wave_sum(acc);
        if (lane == 0) out[o] = sigm(acc + b_out[o]);
    }
}

// ======================= fallback: proven R3 pipeline =======================
__global__ __launch_bounds__(256) void k_gates(const float* __restrict__ x,
                                               const float* __restrict__ pr,
                                               const float* __restrict__ h,
                                               const float* __restrict__ W_ih,
                                               const float* __restrict__ b_ih,
                                               const float* __restrict__ W_hh,
                                               const float* __restrict__ b_hh,
                                               float* __restrict__ ws) {
    const int t = threadIdx.x, lane = t & 63, wv = t >> 6;
    const int o = blockIdx.x * 4 + wv;
    const float* wi = W_ih + (size_t)o * 768;
    const float* wh = W_hh + (size_t)o * 512;
    float acc = dot4(ld4(wi + lane * 4), ld4(x + lane * 4))
              + dot4(ld4(wi + 256 + lane * 4), ld4(pr + lane * 4))
              + dot4(ld4(wi + 512 + lane * 4), ld4(pr + 256 + lane * 4))
              + dot4(ld4(wh + lane * 4), ld4(h + lane * 4))
              + dot4(ld4(wh + 256 + lane * 4), ld4(h + 256 + lane * 4));
    acc = wave_sum(acc);
    if (lane == 0) ws[WS_GATES + o] = acc + b_ih[o] + b_hh[o];
}

__global__ __launch_bounds__(256) void k_hr(const float* __restrict__ c,
                                            const float* __restrict__ W_read,
                                            const float* __restrict__ b_read,
                                            float* __restrict__ ws) {
    __shared__ float sh[512];
    const int t = threadIdx.x;
    for (int j = t; j < 512; j += 256) {
        float ig = ws[WS_GATES + j];
        float fg = ws[WS_GATES + 512 + j];
        float gg = ws[WS_GATES + 1024 + j];
        float og = ws[WS_GATES + 1536 + j];
        float cn = sigm(fg) * c[j] + sigm(ig) * tanhf(gg);
        float hn = sigm(og) * tanhf(cn);
        sh[j] = hn;
        if (blockIdx.x == 0) ws[WS_HNEW + j] = hn;
    }
    __syncthreads();
    const int lane = t & 63, wv = t >> 6;
    const int o = blockIdx.x * 4 + wv;
    if (o >= 518) return;
    const float* wr = W_read + (size_t)o * 512;
    float acc = dot4(ld4(wr + lane * 4), ld4(sh + lane * 4))
              + dot4(ld4(wr + 256 + lane * 4), ld4(sh + 256 + lane * 4));
    acc = wave_sum(acc);
    if (lane == 0) ws[WS_ROUT + o] = acc + b_read[o];
}

__global__ __launch_bounds__(256) void k_cos(const float* __restrict__ mem,
                                             float* __restrict__ ws) {
    const int t = threadIdx.x, lane = t & 63, wv = t >> 6;
    const int gw = blockIdx.x * 4 + wv;
    const float* key = ws + WS_ROUT;
    float4 ka = ld4(key + lane * 4);
    float4 kb = ld4(key + 256 + lane * 4);
    ka.x += EPS; ka.y += EPS; ka.z += EPS; ka.w += EPS;
    kb.x += EPS; kb.y += EPS; kb.z += EPS; kb.w += EPS;
    float kq = wave_sum(dot4(ka, ka) + dot4(kb, kb));
    const float nb = fmaxf(sqrtf(kq), EPS);
    const float beta = softplusf_(key[512]);
    float* sp = ws + WS_S;
    float m = -1e30f, e = 0.f;
    for (int n = gw; n < NN; n += 8192) {
        float4 va = ld4(mem + (size_t)n * 512 + lane * 4);
        float4 vb = ld4(mem + (size_t)n * 512 + 256 + lane * 4);
        va.x += EPS; va.y += EPS; va.z += EPS; va.w += EPS;
        vb.x += EPS; vb.y += EPS; vb.z += EPS; vb.w += EPS;
        float dot = wave_sum(dot4(va, ka) + dot4(vb, kb));
        float sq  = wave_sum(dot4(va, va) + dot4(vb, vb));
        float na = fmaxf(sqrtf(sq), EPS);
        float sv = beta * dot / (na * nb);
        if (lane == 0) sp[n] = sv;
        float nm = fmaxf(m, sv);
        e = e * expf(m - nm) + expf(sv - nm);
        m = nm;
    }
    __shared__ float sm[4], se[4];
    if (lane == 0) { sm[wv] = m; se[wv] = e; }
    __syncthreads();
    if (t == 0) {
        float M = fmaxf(fmaxf(sm[0], sm[1]), fmaxf(sm[2], sm[3]));
        float E = se[0] * expf(sm[0] - M) + se[1] * expf(sm[1] - M) +
                  se[2] * expf(sm[2] - M) + se[3] * expf(sm[3] - M);
        ws[WS_PMAX + blockIdx.x] = M;
        ws[WS_PEXP + blockIdx.x] = E;
    }
}

__global__ __launch_bounds__(512) void k_read(const float* __restrict__ mem,
                                              const float* __restrict__ rs,
                                              float* __restrict__ ws) {
    const int b = blockIdx.x, t = threadIdx.x;
    const int lane = t & 63, wv = t >> 6;
    __shared__ float s_m[8], s_e[8];
    __shared__ float wi_l[258];
    __shared__ float pl[256];
    __shared__ float s_ps[4];
    __shared__ float4 sacc[3][128];

    float m = -1e30f, e = 0.f;
    for (int i = t; i < 2048; i += 512) {
        float bm = ws[WS_PMAX + i], be = ws[WS_PEXP + i];
        float nm = fmaxf(m, bm);
        e = e * expf(m - nm) + be * expf(bm - nm);
        m = nm;
    }
    for (int o = 32; o > 0; o >>= 1) {
        float om = __shfl_xor(m, o), oe = __shfl_xor(e, o);
        float nm = fmaxf(m, om);
        e = e * expf(m - nm) + oe * expf(om - nm);
        m = nm;
    }
    if (lane == 0) { s_m[wv] = m; s_e[wv] = e; }
    __syncthreads();
    float mx = s_m[0];
    for (int i = 1; i < 8; ++i) mx = fmaxf(mx, s_m[i]);
    float Z = 0.f;
    for (int i = 0; i < 8; ++i) Z += s_e[i] * expf(s_m[i] - mx);
    const float invZ = 1.f / Z;
    const float g = sigm(ws[WS_ROUT + 513]);
    float a3 = ws[WS_ROUT + 514], b3 = ws[WS_ROUT + 515], c3 = ws[WS_ROUT + 516];
    float mm = fmaxf(a3, fmaxf(b3, c3));
    float ea = expf(a3 - mm), eb = expf(b3 - mm), ec = expf(c3 - mm);
    float ss = ea + eb + ec;
    const float s0 = ea / ss, s1 = eb / ss, s2 = ec / ss;
    const float gamma = 1.f + softplusf_(ws[WS_ROUT + 517]);

    const int start = b * 256;
    const float* sp = ws + WS_S;
    if (t < 258) {
        int idx = (start - 1 + t) & (NN - 1);
        wi_l[t] = g * rs[idx] + (1.f - g) * expf(sp[idx] - mx) * invZ;
    }
    __syncthreads();
    float ps = 0.f;
    if (t < 256) {
        float wsh = wi_l[t] * s0 + wi_l[t + 1] * s1 + wi_l[t + 2] * s2;
        float pv = powf(wsh, gamma);
        pl[t] = pv;
        ps = pv;
    }
    ps = wave_sum(ps);
    if (t < 256 && lane == 0) s_ps[wv] = ps;
    __syncthreads();
    if (t == 0) ws[WS_PSUM + b] = s_ps[0] + s_ps[1] + s_ps[2] + s_ps[3];

    const int col = (t & 127) * 4;
    const int rq = t >> 7;
    float4 acc = make_float4(0.f, 0.f, 0.f, 0.f);
    const float* basep = mem + (size_t)start * 512 + col;
    #pragma unroll 8
    for (int r = rq; r < 256; r += 4) {
        float w = pl[r];
        float4 v = ld4(basep + (size_t)r * 512);
        acc.x += w * v.x; acc.y += w * v.y; acc.z += w * v.z; acc.w += w * v.w;
    }
    if (rq > 0) sacc[rq - 1][t & 127] = acc;
    __syncthreads();
    if (rq == 0) {
        float4 a0 = sacc[0][t & 127], a1 = sacc[1][t & 127], a2 = sacc[2][t & 127];
        acc.x += a0.x + a1.x + a2.x;
        acc.y += a0.y + a1.y + a2.y;
        acc.z += a0.z + a1.z + a2.z;
        acc.w += a0.w + a1.w + a2.w;
        *(float4*)(ws + WS_PART + (size_t)b * 512 + col) = acc;
    }
}

__global__ __launch_bounds__(256) void k_out(const float* __restrict__ W_out,
                                             const float* __restrict__ b_out,
                                             const float* __restrict__ ws,
                                             float* __restrict__ out) {
    const int t = threadIdx.x, lane = t & 63, wv = t >> 6;
    __shared__ float rd[512];
    __shared__ float s_z[4];
    float z = (t < 256) ? ws[WS_PSUM + t] : 0.f;
    z = wave_sum(z);
    if (lane == 0) s_z[wv] = z;
    float2 acc = make_float2(0.f, 0.f);
    const float* pp = ws + WS_PART + t * 2;
    #pragma unroll 16
    for (int r = 0; r < 256; ++r) {
        float2 v = *(const float2*)(pp + (size_t)r * 512);
        acc.x += v.x; acc.y += v.y;
    }
    __syncthreads();
    const float Zp = s_z[0] + s_z[1] + s_z[2] + s_z[3];
    const float invZp = 1.f / (Zp + EPS);
    rd[2 * t] = acc.x * invZp;
    rd[2 * t + 1] = acc.y * invZp;
    __syncthreads();
    const int o = blockIdx.x * 4 + wv;
    const float* wo = W_out + (size_t)o * 1024;
    float a = dot4(ld4(wo + lane * 4), ld4(ws + WS_HNEW + lane * 4))
            + dot4(ld4(wo + 256 + lane * 4), ld4(ws + WS_HNEW + 256 + lane * 4))
            + dot4(ld4(wo + 512 + lane * 4), ld4(rd + lane * 4))
            + dot4(ld4(wo + 768 + lane * 4), ld4(rd + 256 + lane * 4));
    a = wave_sum(a);
    if (lane == 0) out[o] = sigm(a + b_out[o]);
}

extern "C" void kernel_launch(void* const* d_in, const int* in_sizes, int n_in,
                              void* d_out, int out_size, void* d_ws, size_t ws_size,
                              hipStream_t stream) {
    const float* x          = (const float*)d_in[0];
    const float* memory     = (const float*)d_in[1];
    const float* prev_read  = (const float*)d_in[2];
    const float* h          = (const float*)d_in[3];
    const float* c          = (const float*)d_in[4];
    const float* read_state = (const float*)d_in[5];
    // d_in[6] write_state, d_in[13] W_write, d_in[14] b_write: dead in reference
    const float* W_ih   = (const float*)d_in[7];
    const float* b_ih   = (const float*)d_in[8];
    const float* W_hh   = (const float*)d_in[9];
    const float* b_hh   = (const float*)d_in[10];
    const float* W_read = (const float*)d_in[11];
    const float* b_read = (const float*)d_in[12];
    const float* W_out  = (const float*)d_in[15];
    const float* b_out  = (const float*)d_in[16];
    float* ws  = (float*)d_ws;
    float* out = (float*)d_out;

    void* args[] = {
        (void*)&x, (void*)&memory, (void*)&prev_read, (void*)&h, (void*)&c,
        (void*)&read_state, (void*)&W_ih, (void*)&b_ih, (void*)&W_hh,
        (void*)&b_hh, (void*)&W_read, (void*)&b_read, (void*)&W_out,
        (void*)&b_out, (void*)&ws, (void*)&out
    };
    hipError_t cerr = hipLaunchCooperativeKernel((void*)k_fused, dim3(512),
                                                 dim3(256), args, 0, stream);
    if (cerr != hipSuccess) {
        (void)hipGetLastError();  // clear error state, take proven split path
        k_gates<<<512, 256, 0, stream>>>(x, prev_read, h, W_ih, b_ih, W_hh, b_hh, ws);
        k_hr<<<130, 256, 0, stream>>>(c, W_read, b_read, ws);
        k_cos<<<2048, 256, 0, stream>>>(memory, ws);
        k_read<<<256, 512, 0, stream>>>(memory, read_state, ws);
        k_out<<<64, 256, 0, stream>>>(W_out, b_out, ws, out);
    }
}

// Round 6
// 141.327 us; speedup vs baseline: 2.4576x; 2.4576x over previous
//
#include <hip/hip_runtime.h>
#include <math.h>

#define EPS 1e-8f
#define NN 65536

// ---- fused (custom-barrier) ws layout, float offsets ----
#define FB_BAR   0       // 512 u32 barrier state (memset 0 each launch)
#define FB_HNEW  512     // 512
#define FB_ROUT  1024    // 518 (pad 520)
#define FB_PMAX  1568    // 512
#define FB_PEXP  2080    // 512
#define FB_S     2592    // 65536
#define FB_PSUM  68128   // 512
#define FB_PART  68640   // 512*512
#define FB_PART2 330784  // 64*512  (end 363552 floats ~1.45 MB)

// ---- fallback (R3-proven) ws layout ----
#define WS_GATES 0
#define WS_HNEW  2048
#define WS_ROUT  2560
#define WS_PMAX  3104
#define WS_PEXP  5152
#define WS_S     7200
#define WS_PSUM  72736
#define WS_PART  72992

__device__ __forceinline__ float wave_sum(float v) {
    for (int o = 32; o > 0; o >>= 1) v += __shfl_xor(v, o);
    return v;
}
__device__ __forceinline__ float sigm(float x) { return 1.f / (1.f + expf(-x)); }
__device__ __forceinline__ float softplusf_(float x) {
    return x > 20.f ? x : log1pf(expf(x));
}
__device__ __forceinline__ float dot4(float4 a, float4 b) {
    return a.x * b.x + a.y * b.y + a.z * b.z + a.w * b.w;
}
__device__ __forceinline__ float4 ld4(const float* p) { return *(const float4*)p; }

// ---- agent-scope coherent (L2-bypass) accessors for cross-block ws data ----
__device__ __forceinline__ float ald(const float* p) {
    return __hip_atomic_load(p, __ATOMIC_RELAXED, __HIP_MEMORY_SCOPE_AGENT);
}
__device__ __forceinline__ void ast(float* p, float v) {
    __hip_atomic_store(p, v, __ATOMIC_RELAXED, __HIP_MEMORY_SCOPE_AGENT);
}
__device__ __forceinline__ float2 ald2(const float* p) {
    unsigned long long u = __hip_atomic_load((const unsigned long long*)p,
        __ATOMIC_RELAXED, __HIP_MEMORY_SCOPE_AGENT);
    float2 r; __builtin_memcpy(&r, &u, 8); return r;
}
__device__ __forceinline__ void ast2(float* p, float2 v) {
    unsigned long long u; __builtin_memcpy(&u, &v, 8);
    __hip_atomic_store((unsigned long long*)p, u,
        __ATOMIC_RELAXED, __HIP_MEMORY_SCOPE_AGENT);
}

// Two-level grid barrier. 512 blocks; 8 sub-counters (line-padded) -> master -> gen.
// All cross-phase data uses agent-scope atomics (coherence point), so no cache
// writeback/invalidate is needed -- this is why it beats cg::grid_group::sync.
__device__ __forceinline__ void gbar(unsigned* bar) {
    __syncthreads();
    if (threadIdx.x == 0) {
        unsigned* sub = bar + 32 * (blockIdx.x & 7);
        unsigned* mst = bar + 256;
        unsigned* gen = bar + 288;
        unsigned g = __hip_atomic_load(gen, __ATOMIC_RELAXED, __HIP_MEMORY_SCOPE_AGENT);
        unsigned so = __hip_atomic_fetch_add(sub, 1u, __ATOMIC_ACQ_REL,
                                             __HIP_MEMORY_SCOPE_AGENT);
        if (so == 63u) {
            __hip_atomic_store(sub, 0u, __ATOMIC_RELAXED, __HIP_MEMORY_SCOPE_AGENT);
            unsigned mo = __hip_atomic_fetch_add(mst, 1u, __ATOMIC_ACQ_REL,
                                                 __HIP_MEMORY_SCOPE_AGENT);
            if (mo == 7u) {
                __hip_atomic_store(mst, 0u, __ATOMIC_RELAXED, __HIP_MEMORY_SCOPE_AGENT);
                __hip_atomic_fetch_add(gen, 1u, __ATOMIC_RELEASE,
                                       __HIP_MEMORY_SCOPE_AGENT);
            }
        }
        int cap = 0;
        while (__hip_atomic_load(gen, __ATOMIC_RELAXED, __HIP_MEMORY_SCOPE_AGENT) == g) {
            __builtin_amdgcn_s_sleep(2);
            if (++cap > (1 << 22)) break;  // fail loud (validation) instead of hang
        }
    }
    __syncthreads();
}

// ============ fused persistent kernel: 512 blocks x 512 threads ============
__global__ __launch_bounds__(512, 4) void k_fused(
    const float* __restrict__ x, const float* __restrict__ mem,
    const float* __restrict__ pr, const float* __restrict__ h,
    const float* __restrict__ c, const float* __restrict__ rs,
    const float* __restrict__ W_ih, const float* __restrict__ b_ih,
    const float* __restrict__ W_hh, const float* __restrict__ b_hh,
    const float* __restrict__ W_read, const float* __restrict__ b_read,
    const float* __restrict__ W_out, const float* __restrict__ b_out,
    float* __restrict__ ws, float* __restrict__ out)
{
    const int b = blockIdx.x, t = threadIdx.x;
    const int lane = t & 63, wv = t >> 6;
    unsigned* bar = (unsigned*)ws;

    __shared__ float shn[520];
    __shared__ float rd[512];
    __shared__ float sred[16];
    __shared__ float smre[16];
    __shared__ float wi_l[130];
    __shared__ float pl[128];
    __shared__ float shs[8];
    __shared__ float4 sacc[3][128];

    // ---- P1: gates + LSTM, block b = channel b; waves 0-3 = gates i,f,g,o ----
    if (wv < 4) {
        const int row = wv * 512 + b;
        const float* wi = W_ih + (size_t)row * 768;
        const float* wh = W_hh + (size_t)row * 512;
        float acc = dot4(ld4(wi + lane * 4), ld4(x + lane * 4))
                  + dot4(ld4(wi + 256 + lane * 4), ld4(pr + lane * 4))
                  + dot4(ld4(wi + 512 + lane * 4), ld4(pr + 256 + lane * 4))
                  + dot4(ld4(wh + lane * 4), ld4(h + lane * 4))
                  + dot4(ld4(wh + 256 + lane * 4), ld4(h + 256 + lane * 4));
        acc = wave_sum(acc);
        if (lane == 0) sred[wv] = acc + b_ih[row] + b_hh[row];
    }
    __syncthreads();
    if (t == 0) {
        float ig = sred[0], fg = sred[1], gg = sred[2], og = sred[3];
        float cn = sigm(fg) * c[b] + sigm(ig) * tanhf(gg);
        ast(ws + FB_HNEW + b, sigm(og) * tanhf(cn));
    }
    gbar(bar);

    // ---- P2: r_out (blocks 0..64, wave per output) ----
    if (b < 65) {
        shn[t] = ald(ws + FB_HNEW + t);
        __syncthreads();
        const int o = b * 8 + wv;
        if (o < 518) {
            const float* wr = W_read + (size_t)o * 512;
            float acc = dot4(ld4(wr + lane * 4), ld4(shn + lane * 4))
                      + dot4(ld4(wr + 256 + lane * 4), ld4(shn + 256 + lane * 4));
            acc = wave_sum(acc);
            if (lane == 0) ast(ws + FB_ROUT + o, acc + b_read[o]);
        }
    }
    gbar(bar);

    // ---- P3: cosine scores; 4096 waves, 16 rows each; per-block (max,expsum) ----
    {
        if (t < 513) shn[t] = ald(ws + FB_ROUT + t);
        __syncthreads();
        float4 ka = ld4(shn + lane * 4);
        float4 kb = ld4(shn + 256 + lane * 4);
        ka.x += EPS; ka.y += EPS; ka.z += EPS; ka.w += EPS;
        kb.x += EPS; kb.y += EPS; kb.z += EPS; kb.w += EPS;
        const float nb_ = fmaxf(sqrtf(wave_sum(dot4(ka, ka) + dot4(kb, kb))), EPS);
        const float beta = softplusf_(shn[512]);
        const int w = b * 8 + wv;  // [0,4096)
        float m = -1e30f, e = 0.f;
        for (int i = 0; i < 16; ++i) {
            const int n = w + i * 4096;
            float4 va = ld4(mem + (size_t)n * 512 + lane * 4);
            float4 vb = ld4(mem + (size_t)n * 512 + 256 + lane * 4);
            va.x += EPS; va.y += EPS; va.z += EPS; va.w += EPS;
            vb.x += EPS; vb.y += EPS; vb.z += EPS; vb.w += EPS;
            float d = dot4(va, ka) + dot4(vb, kb);
            float q = dot4(va, va) + dot4(vb, vb);
            for (int o = 32; o > 0; o >>= 1) {
                d += __shfl_xor(d, o);
                q += __shfl_xor(q, o);
            }
            float sv = beta * d / (fmaxf(sqrtf(q), EPS) * nb_);
            if (lane == 0) ast(ws + FB_S + n, sv);
            float nm = fmaxf(m, sv);
            e = e * expf(m - nm) + expf(sv - nm);
            m = nm;
        }
        __syncthreads();  // shn reuse done
        if (lane == 0) { sred[wv] = m; smre[wv] = e; }
        __syncthreads();
        if (t == 0) {
            float M = sred[0], E;
            for (int i = 1; i < 8; ++i) M = fmaxf(M, sred[i]);
            E = 0.f;
            for (int i = 0; i < 8; ++i) E += smre[i] * expf(sred[i] - M);
            ast(ws + FB_PMAX + b, M);
            ast(ws + FB_PEXP + b, E);
        }
    }
    gbar(bar);

    // ---- P4: global stats (redundant per block) + p + column partials ----
    {
        float m = ald(ws + FB_PMAX + t);
        float e = ald(ws + FB_PEXP + t);
        for (int o = 32; o > 0; o >>= 1) {
            float om = __shfl_xor(m, o), oe = __shfl_xor(e, o);
            float nm = fmaxf(m, om);
            e = e * expf(m - nm) + oe * expf(om - nm);
            m = nm;
        }
        if (lane == 0) { sred[wv] = m; smre[wv] = e; }
        if (t < 5) shs[t] = ald(ws + FB_ROUT + 513 + t);
        __syncthreads();
        float mx = sred[0];
        for (int i = 1; i < 8; ++i) mx = fmaxf(mx, sred[i]);
        float Z = 0.f;
        for (int i = 0; i < 8; ++i) Z += smre[i] * expf(sred[i] - mx);
        const float invZ = 1.f / Z;
        const float g = sigm(shs[0]);
        float a3 = shs[1], b3 = shs[2], c3 = shs[3];
        float mm = fmaxf(a3, fmaxf(b3, c3));
        float ea = expf(a3 - mm), eb = expf(b3 - mm), ec = expf(c3 - mm);
        float ssum = ea + eb + ec;
        const float s0 = ea / ssum, s1 = eb / ssum, s2 = ec / ssum;
        const float gamma = 1.f + softplusf_(shs[4]);

        const int start = b * 128;
        if (t < 130) {
            int idx = (start - 1 + t) & (NN - 1);
            wi_l[t] = g * rs[idx] + (1.f - g) * expf(ald(ws + FB_S + idx) - mx) * invZ;
        }
        __syncthreads();
        float ps = 0.f;
        if (t < 128) {
            float wsh = wi_l[t] * s0 + wi_l[t + 1] * s1 + wi_l[t + 2] * s2;
            float pv = powf(wsh, gamma);
            pl[t] = pv;
            ps = pv;
        }
        ps = wave_sum(ps);
        if (t < 128 && lane == 0) smre[8 + wv] = ps;
        __syncthreads();
        if (t == 0) ast(ws + FB_PSUM + b, smre[8] + smre[9]);

        const int col = (t & 127) * 4, rh = t >> 7;  // rh in [0,4)
        float4 acc = make_float4(0.f, 0.f, 0.f, 0.f);
        const float* basep = mem + (size_t)start * 512 + col;
        #pragma unroll 8
        for (int r = rh; r < 128; r += 4) {
            float w = pl[r];
            float4 v = ld4(basep + (size_t)r * 512);
            acc.x += w * v.x; acc.y += w * v.y; acc.z += w * v.z; acc.w += w * v.w;
        }
        if (rh) sacc[rh - 1][t & 127] = acc;
        __syncthreads();
        if (rh == 0) {
            float4 a0 = sacc[0][t & 127], a1 = sacc[1][t & 127], a2 = sacc[2][t & 127];
            acc.x += a0.x + a1.x + a2.x;
            acc.y += a0.y + a1.y + a2.y;
            acc.z += a0.z + a1.z + a2.z;
            acc.w += a0.w + a1.w + a2.w;
            float* pp = ws + FB_PART + (size_t)b * 512 + col;
            ast2(pp, make_float2(acc.x, acc.y));
            ast2(pp + 2, make_float2(acc.z, acc.w));
        }
    }
    gbar(bar);

    // ---- P5: PART2[64][512] = 8-row sums of PART ----
    if (b < 64) {
        float a = 0.f;
        const float* pp = ws + FB_PART + (size_t)b * 8 * 512 + t;
        #pragma unroll
        for (int r = 0; r < 8; ++r) a += ald(pp + r * 512);
        ast(ws + FB_PART2 + (size_t)b * 512 + t, a);
    }
    gbar(bar);

    // ---- P6: Zp + read + out (blocks 0..63) ----
    if (b < 64) {
        float z = ald(ws + FB_PSUM + t);
        z = wave_sum(z);
        if (lane == 0) sred[wv] = z;
        shn[t] = ald(ws + FB_HNEW + t);
        __syncthreads();
        float Zp = 0.f;
        for (int i = 0; i < 8; ++i) Zp += sred[i];
        const float invZp = 1.f / (Zp + EPS);
        if (t < 256) {
            float ax = 0.f, ay = 0.f;
            const float* p2 = ws + FB_PART2 + t * 2;
            #pragma unroll 8
            for (int r = 0; r < 64; ++r) {
                float2 v = ald2(p2 + (size_t)r * 512);
                ax += v.x; ay += v.y;
            }
            rd[2 * t] = ax * invZp;
            rd[2 * t + 1] = ay * invZp;
        }
        __syncthreads();
        if (wv < 4) {
            const int o = b * 4 + wv;
            const float* wo = W_out + (size_t)o * 1024;
            float acc = dot4(ld4(wo + lane * 4), ld4(shn + lane * 4))
                      + dot4(ld4(wo + 256 + lane * 4), ld4(shn + 256 + lane * 4))
                      + dot4(ld4(wo + 512 + lane * 4), ld4(rd + lane * 4))
                      + dot4(ld4(wo + 768 + lane * 4), ld4(rd + 256 + lane * 4));
            acc = wave_sum(acc);
            if (lane == 0) out[o] = sigm(acc + b_out[o]);
        }
    }
}

// ======================= fallback: proven R3 pipeline =======================
__global__ __launch_bounds__(256) void k_gates(const float* __restrict__ x,
                                               const float* __restrict__ pr,
                                               const float* __restrict__ h,
                                               const float* __restrict__ W_ih,
                                               const float* __restrict__ b_ih,
                                               const float* __restrict__ W_hh,
                                               const float* __restrict__ b_hh,
                                               float* __restrict__ ws) {
    const int t = threadIdx.x, lane = t & 63, wv = t >> 6;
    const int o = blockIdx.x * 4 + wv;
    const float* wi = W_ih + (size_t)o * 768;
    const float* wh = W_hh + (size_t)o * 512;
    float acc = dot4(ld4(wi + lane * 4), ld4(x + lane * 4))
              + dot4(ld4(wi + 256 + lane * 4), ld4(pr + lane * 4))
              + dot4(ld4(wi + 512 + lane * 4), ld4(pr + 256 + lane * 4))
              + dot4(ld4(wh + lane * 4), ld4(h + lane * 4))
              + dot4(ld4(wh + 256 + lane * 4), ld4(h + 256 + lane * 4));
    acc = wave_sum(acc);
    if (lane == 0) ws[WS_GATES + o] = acc + b_ih[o] + b_hh[o];
}

__global__ __launch_bounds__(256) void k_hr(const float* __restrict__ c,
                                            const float* __restrict__ W_read,
                                            const float* __restrict__ b_read,
                                            float* __restrict__ ws) {
    __shared__ float sh[512];
    const int t = threadIdx.x;
    for (int j = t; j < 512; j += 256) {
        float ig = ws[WS_GATES + j];
        float fg = ws[WS_GATES + 512 + j];
        float gg = ws[WS_GATES + 1024 + j];
        float og = ws[WS_GATES + 1536 + j];
        float cn = sigm(fg) * c[j] + sigm(ig) * tanhf(gg);
        float hn = sigm(og) * tanhf(cn);
        sh[j] = hn;
        if (blockIdx.x == 0) ws[WS_HNEW + j] = hn;
    }
    __syncthreads();
    const int lane = t & 63, wv = t >> 6;
    const int o = blockIdx.x * 4 + wv;
    if (o >= 518) return;
    const float* wr = W_read + (size_t)o * 512;
    float acc = dot4(ld4(wr + lane * 4), ld4(sh + lane * 4))
              + dot4(ld4(wr + 256 + lane * 4), ld4(sh + 256 + lane * 4));
    acc = wave_sum(acc);
    if (lane == 0) ws[WS_ROUT + o] = acc + b_read[o];
}

__global__ __launch_bounds__(256) void k_cos(const float* __restrict__ mem,
                                             float* __restrict__ ws) {
    const int t = threadIdx.x, lane = t & 63, wv = t >> 6;
    const int gw = blockIdx.x * 4 + wv;
    const float* key = ws + WS_ROUT;
    float4 ka = ld4(key + lane * 4);
    float4 kb = ld4(key + 256 + lane * 4);
    ka.x += EPS; ka.y += EPS; ka.z += EPS; ka.w += EPS;
    kb.x += EPS; kb.y += EPS; kb.z += EPS; kb.w += EPS;
    float kq = wave_sum(dot4(ka, ka) + dot4(kb, kb));
    const float nb = fmaxf(sqrtf(kq), EPS);
    const float beta = softplusf_(key[512]);
    float* sp = ws + WS_S;
    float m = -1e30f, e = 0.f;
    for (int n = gw; n < NN; n += 8192) {
        float4 va = ld4(mem + (size_t)n * 512 + lane * 4);
        float4 vb = ld4(mem + (size_t)n * 512 + 256 + lane * 4);
        va.x += EPS; va.y += EPS; va.z += EPS; va.w += EPS;
        vb.x += EPS; vb.y += EPS; vb.z += EPS; vb.w += EPS;
        float dot = wave_sum(dot4(va, ka) + dot4(vb, kb));
        float sq  = wave_sum(dot4(va, va) + dot4(vb, vb));
        float na = fmaxf(sqrtf(sq), EPS);
        float sv = beta * dot / (na * nb);
        if (lane == 0) sp[n] = sv;
        float nm = fmaxf(m, sv);
        e = e * expf(m - nm) + expf(sv - nm);
        m = nm;
    }
    __shared__ float sm[4], se[4];
    if (lane == 0) { sm[wv] = m; se[wv] = e; }
    __syncthreads();
    if (t == 0) {
        float M = fmaxf(fmaxf(sm[0], sm[1]), fmaxf(sm[2], sm[3]));
        float E = se[0] * expf(sm[0] - M) + se[1] * expf(sm[1] - M) +
                  se[2] * expf(sm[2] - M) + se[3] * expf(sm[3] - M);
        ws[WS_PMAX + blockIdx.x] = M;
        ws[WS_PEXP + blockIdx.x] = E;
    }
}

__global__ __launch_bounds__(512) void k_read(const float* __restrict__ mem,
                                              const float* __restrict__ rs,
                                              float* __restrict__ ws) {
    const int b = blockIdx.x, t = threadIdx.x;
    const int lane = t & 63, wv = t >> 6;
    __shared__ float s_m[8], s_e[8];
    __shared__ float wi_l[258];
    __shared__ float pl[256];
    __shared__ float s_ps[4];
    __shared__ float4 sacc[3][128];

    float m = -1e30f, e = 0.f;
    for (int i = t; i < 2048; i += 512) {
        float bm = ws[WS_PMAX + i], be = ws[WS_PEXP + i];
        float nm = fmaxf(m, bm);
        e = e * expf(m - nm) + be * expf(bm - nm);
        m = nm;
    }
    for (int o = 32; o > 0; o >>= 1) {
        float om = __shfl_xor(m, o), oe = __shfl_xor(e, o);
        float nm = fmaxf(m, om);
        e = e * expf(m - nm) + oe * expf(om - nm);
        m = nm;
    }
    if (lane == 0) { s_m[wv] = m; s_e[wv] = e; }
    __syncthreads();
    float mx = s_m[0];
    for (int i = 1; i < 8; ++i) mx = fmaxf(mx, s_m[i]);
    float Z = 0.f;
    for (int i = 0; i < 8; ++i) Z += s_e[i] * expf(s_m[i] - mx);
    const float invZ = 1.f / Z;
    const float g = sigm(ws[WS_ROUT + 513]);
    float a3 = ws[WS_ROUT + 514], b3 = ws[WS_ROUT + 515], c3 = ws[WS_ROUT + 516];
    float mm = fmaxf(a3, fmaxf(b3, c3));
    float ea = expf(a3 - mm), eb = expf(b3 - mm), ec = expf(c3 - mm);
    float ss = ea + eb + ec;
    const float s0 = ea / ss, s1 = eb / ss, s2 = ec / ss;
    const float gamma = 1.f + softplusf_(ws[WS_ROUT + 517]);

    const int start = b * 256;
    const float* sp = ws + WS_S;
    if (t < 258) {
        int idx = (start - 1 + t) & (NN - 1);
        wi_l[t] = g * rs[idx] + (1.f - g) * expf(sp[idx] - mx) * invZ;
    }
    __syncthreads();
    float ps = 0.f;
    if (t < 256) {
        float wsh = wi_l[t] * s0 + wi_l[t + 1] * s1 + wi_l[t + 2] * s2;
        float pv = powf(wsh, gamma);
        pl[t] = pv;
        ps = pv;
    }
    ps = wave_sum(ps);
    if (t < 256 && lane == 0) s_ps[wv] = ps;
    __syncthreads();
    if (t == 0) ws[WS_PSUM + b] = s_ps[0] + s_ps[1] + s_ps[2] + s_ps[3];

    const int col = (t & 127) * 4;
    const int rq = t >> 7;
    float4 acc = make_float4(0.f, 0.f, 0.f, 0.f);
    const float* basep = mem + (size_t)start * 512 + col;
    #pragma unroll 8
    for (int r = rq; r < 256; r += 4) {
        float w = pl[r];
        float4 v = ld4(basep + (size_t)r * 512);
        acc.x += w * v.x; acc.y += w * v.y; acc.z += w * v.z; acc.w += w * v.w;
    }
    if (rq > 0) sacc[rq - 1][t & 127] = acc;
    __syncthreads();
    if (rq == 0) {
        float4 a0 = sacc[0][t & 127], a1 = sacc[1][t & 127], a2 = sacc[2][t & 127];
        acc.x += a0.x + a1.x + a2.x;
        acc.y += a0.y + a1.y + a2.y;
        acc.z += a0.z + a1.z + a2.z;
        acc.w += a0.w + a1.w + a2.w;
        *(float4*)(ws + WS_PART + (size_t)b * 512 + col) = acc;
    }
}

__global__ __launch_bounds__(256) void k_out(const float* __restrict__ W_out,
                                             const float* __restrict__ b_out,
                                             const float* __restrict__ ws,
                                             float* __restrict__ out) {
    const int t = threadIdx.x, lane = t & 63, wv = t >> 6;
    __shared__ float rd[512];
    __shared__ float s_z[4];
    float z = (t < 256) ? ws[WS_PSUM + t] : 0.f;
    z = wave_sum(z);
    if (lane == 0) s_z[wv] = z;
    float2 acc = make_float2(0.f, 0.f);
    const float* pp = ws + WS_PART + t * 2;
    #pragma unroll 16
    for (int r = 0; r < 256; ++r) {
        float2 v = *(const float2*)(pp + (size_t)r * 512);
        acc.x += v.x; acc.y += v.y;
    }
    __syncthreads();
    const float Zp = s_z[0] + s_z[1] + s_z[2] + s_z[3];
    const float invZp = 1.f / (Zp + EPS);
    rd[2 * t] = acc.x * invZp;
    rd[2 * t + 1] = acc.y * invZp;
    __syncthreads();
    const int o = blockIdx.x * 4 + wv;
    const float* wo = W_out + (size_t)o * 1024;
    float a = dot4(ld4(wo + lane * 4), ld4(ws + WS_HNEW + lane * 4))
            + dot4(ld4(wo + 256 + lane * 4), ld4(ws + WS_HNEW + 256 + lane * 4))
            + dot4(ld4(wo + 512 + lane * 4), ld4(rd + lane * 4))
            + dot4(ld4(wo + 768 + lane * 4), ld4(rd + 256 + lane * 4));
    a = wave_sum(a);
    if (lane == 0) out[o] = sigm(a + b_out[o]);
}

extern "C" void kernel_launch(void* const* d_in, const int* in_sizes, int n_in,
                              void* d_out, int out_size, void* d_ws, size_t ws_size,
                              hipStream_t stream) {
    const float* x          = (const float*)d_in[0];
    const float* memory     = (const float*)d_in[1];
    const float* prev_read  = (const float*)d_in[2];
    const float* h          = (const float*)d_in[3];
    const float* c          = (const float*)d_in[4];
    const float* read_state = (const float*)d_in[5];
    // d_in[6] write_state, d_in[13] W_write, d_in[14] b_write: dead in reference
    const float* W_ih   = (const float*)d_in[7];
    const float* b_ih   = (const float*)d_in[8];
    const float* W_hh   = (const float*)d_in[9];
    const float* b_hh   = (const float*)d_in[10];
    const float* W_read = (const float*)d_in[11];
    const float* b_read = (const float*)d_in[12];
    const float* W_out  = (const float*)d_in[15];
    const float* b_out  = (const float*)d_in[16];
    float* ws  = (float*)d_ws;
    float* out = (float*)d_out;

    // zero the barrier state (512 u32) -- graph-capturable async memset
    hipMemsetAsync(ws, 0, 2048, stream);

    void* args[] = {
        (void*)&x, (void*)&memory, (void*)&prev_read, (void*)&h, (void*)&c,
        (void*)&read_state, (void*)&W_ih, (void*)&b_ih, (void*)&W_hh,
        (void*)&b_hh, (void*)&W_read, (void*)&b_read, (void*)&W_out,
        (void*)&b_out, (void*)&ws, (void*)&out
    };
    hipError_t cerr = hipLaunchCooperativeKernel((void*)k_fused, dim3(512),
                                                 dim3(512), args, 0, stream);
    if (cerr != hipSuccess) {
        (void)hipGetLastError();  // clear, take proven split path
        k_gates<<<512, 256, 0, stream>>>(x, prev_read, h, W_ih, b_ih, W_hh, b_hh, ws);
        k_hr<<<130, 256, 0, stream>>>(c, W_read, b_read, ws);
        k_cos<<<2048, 256, 0, stream>>>(memory, ws);
        k_read<<<256, 512, 0, stream>>>(memory, read_state, ws);
        k_out<<<64, 256, 0, stream>>>(W_out, b_out, ws, out);
    }
}

// Round 7
// 80.704 us; speedup vs baseline: 4.3036x; 1.7512x over previous
//
#include <hip/hip_runtime.h>
#include <math.h>

#define EPS 1e-8f
#define NN 65536

// ws float offsets (R3-proven layout)
#define WS_GATES 0       // 2048
#define WS_HNEW  2048    // 512
#define WS_ROUT  2560    // 518
#define WS_PMAX  3104    // 2048
#define WS_PEXP  5152    // 2048
#define WS_S     7200    // 65536
#define WS_PSUM  72736   // 256
#define WS_PART  72992   // 256*512

__device__ __forceinline__ float wave_sum(float v) {
    for (int o = 32; o > 0; o >>= 1) v += __shfl_xor(v, o);
    return v;
}
__device__ __forceinline__ float sigm(float x) { return 1.f / (1.f + expf(-x)); }
__device__ __forceinline__ float softplusf_(float x) {
    return x > 20.f ? x : log1pf(expf(x));
}
__device__ __forceinline__ float dot4(float4 a, float4 b) {
    return a.x * b.x + a.y * b.y + a.z * b.z + a.w * b.w;
}
__device__ __forceinline__ float4 ld4(const float* p) { return *(const float4*)p; }

// K1: gates[o] = W_ih[o,:].[x,pr] + b_ih[o] + W_hh[o,:].h + b_hh[o]
__global__ __launch_bounds__(256) void k_gates(const float* __restrict__ x,
                                               const float* __restrict__ pr,
                                               const float* __restrict__ h,
                                               const float* __restrict__ W_ih,
                                               const float* __restrict__ b_ih,
                                               const float* __restrict__ W_hh,
                                               const float* __restrict__ b_hh,
                                               float* __restrict__ ws) {
    const int t = threadIdx.x, lane = t & 63, wv = t >> 6;
    const int o = blockIdx.x * 4 + wv;
    const float* wi = W_ih + (size_t)o * 768;
    const float* wh = W_hh + (size_t)o * 512;
    float acc = dot4(ld4(wi + lane * 4), ld4(x + lane * 4))
              + dot4(ld4(wi + 256 + lane * 4), ld4(pr + lane * 4))
              + dot4(ld4(wi + 512 + lane * 4), ld4(pr + 256 + lane * 4))
              + dot4(ld4(wh + lane * 4), ld4(h + lane * 4))
              + dot4(ld4(wh + 256 + lane * 4), ld4(h + 256 + lane * 4));
    acc = wave_sum(acc);
    if (lane == 0) ws[WS_GATES + o] = acc + b_ih[o] + b_hh[o];
}

// K2: h_new (recomputed per block in LDS) + r_out
__global__ __launch_bounds__(256) void k_hr(const float* __restrict__ c,
                                            const float* __restrict__ W_read,
                                            const float* __restrict__ b_read,
                                            float* __restrict__ ws) {
    __shared__ float sh[512];
    const int t = threadIdx.x;
    for (int j = t; j < 512; j += 256) {
        float ig = ws[WS_GATES + j];
        float fg = ws[WS_GATES + 512 + j];
        float gg = ws[WS_GATES + 1024 + j];
        float og = ws[WS_GATES + 1536 + j];
        float cn = sigm(fg) * c[j] + sigm(ig) * tanhf(gg);
        float hn = sigm(og) * tanhf(cn);
        sh[j] = hn;
        if (blockIdx.x == 0) ws[WS_HNEW + j] = hn;
    }
    __syncthreads();
    const int lane = t & 63, wv = t >> 6;
    const int o = blockIdx.x * 4 + wv;
    if (o >= 518) return;
    const float* wr = W_read + (size_t)o * 512;
    float acc = dot4(ld4(wr + lane * 4), ld4(sh + lane * 4))
              + dot4(ld4(wr + 256 + lane * 4), ld4(sh + 256 + lane * 4));
    acc = wave_sum(acc);
    if (lane == 0) ws[WS_ROUT + o] = acc + b_read[o];
}

// K3: s[n] = beta*cos(mem[n]+eps, key+eps); per-block online (max, expsum)
__global__ __launch_bounds__(256) void k_cos(const float* __restrict__ mem,
                                             float* __restrict__ ws) {
    const int t = threadIdx.x, lane = t & 63, wv = t >> 6;
    const int gw = blockIdx.x * 4 + wv;
    const float* key = ws + WS_ROUT;
    float4 ka = ld4(key + lane * 4);
    float4 kb = ld4(key + 256 + lane * 4);
    ka.x += EPS; ka.y += EPS; ka.z += EPS; ka.w += EPS;
    kb.x += EPS; kb.y += EPS; kb.z += EPS; kb.w += EPS;
    float kq = wave_sum(dot4(ka, ka) + dot4(kb, kb));
    const float nb = fmaxf(sqrtf(kq), EPS);
    const float beta = softplusf_(key[512]);
    float* sp = ws + WS_S;
    float m = -1e30f, e = 0.f;
    for (int n = gw; n < NN; n += 8192) {
        float4 va = ld4(mem + (size_t)n * 512 + lane * 4);
        float4 vb = ld4(mem + (size_t)n * 512 + 256 + lane * 4);
        va.x += EPS; va.y += EPS; va.z += EPS; va.w += EPS;
        vb.x += EPS; vb.y += EPS; vb.z += EPS; vb.w += EPS;
        float dot = wave_sum(dot4(va, ka) + dot4(vb, kb));
        float sq  = wave_sum(dot4(va, va) + dot4(vb, vb));
        float na = fmaxf(sqrtf(sq), EPS);
        float sv = beta * dot / (na * nb);
        if (lane == 0) sp[n] = sv;
        float nm = fmaxf(m, sv);
        e = e * expf(m - nm) + expf(sv - nm);
        m = nm;
    }
    __shared__ float sm[4], se[4];
    if (lane == 0) { sm[wv] = m; se[wv] = e; }
    __syncthreads();
    if (t == 0) {
        float M = fmaxf(fmaxf(sm[0], sm[1]), fmaxf(sm[2], sm[3]));
        float E = se[0] * expf(sm[0] - M) + se[1] * expf(sm[1] - M) +
                  se[2] * expf(sm[2] - M) + se[3] * expf(sm[3] - M);
        ws[WS_PMAX + blockIdx.x] = M;
        ws[WS_PEXP + blockIdx.x] = E;
    }
}

// K4: fused stats + p + partial column sums. 256 blocks x 1024 threads,
// block owns 256 rows; thread t: col4=(t&127)*4, row-octile rq=t>>7 in [0,8).
__global__ __launch_bounds__(1024) void k_read(const float* __restrict__ mem,
                                               const float* __restrict__ rs,
                                               float* __restrict__ ws) {
    const int b = blockIdx.x, t = threadIdx.x;
    const int lane = t & 63, wv = t >> 6;
    __shared__ float s_m[16], s_e[16];
    __shared__ float wi_l[258];
    __shared__ float pl[256];
    __shared__ float s_ps[4];
    __shared__ float4 sacc[7][128];

    // --- redundant global softmax stats from 2048 (max, expsum) partials ---
    float m = -1e30f, e = 0.f;
    for (int i = t; i < 2048; i += 1024) {
        float bm = ws[WS_PMAX + i], be = ws[WS_PEXP + i];
        float nm = fmaxf(m, bm);
        e = e * expf(m - nm) + be * expf(bm - nm);
        m = nm;
    }
    for (int o = 32; o > 0; o >>= 1) {
        float om = __shfl_xor(m, o), oe = __shfl_xor(e, o);
        float nm = fmaxf(m, om);
        e = e * expf(m - nm) + oe * expf(om - nm);
        m = nm;
    }
    if (lane == 0) { s_m[wv] = m; s_e[wv] = e; }
    __syncthreads();
    float mx = s_m[0];
    for (int i = 1; i < 16; ++i) mx = fmaxf(mx, s_m[i]);
    float Z = 0.f;
    for (int i = 0; i < 16; ++i) Z += s_e[i] * expf(s_m[i] - mx);
    const float invZ = 1.f / Z;
    // --- head scalars (redundant per thread, deterministic) ---
    const float g = sigm(ws[WS_ROUT + 513]);
    float a3 = ws[WS_ROUT + 514], b3 = ws[WS_ROUT + 515], c3 = ws[WS_ROUT + 516];
    float mm = fmaxf(a3, fmaxf(b3, c3));
    float ea = expf(a3 - mm), eb = expf(b3 - mm), ec = expf(c3 - mm);
    float ss = ea + eb + ec;
    const float s0 = ea / ss, s1 = eb / ss, s2 = ec / ss;
    const float gamma = 1.f + softplusf_(ws[WS_ROUT + 517]);

    // --- p for rows [b*256, b*256+256) ---
    const int start = b * 256;
    const float* sp = ws + WS_S;
    if (t < 258) {
        int idx = (start - 1 + t) & (NN - 1);
        wi_l[t] = g * rs[idx] + (1.f - g) * expf(sp[idx] - mx) * invZ;
    }
    __syncthreads();
    float ps = 0.f;
    if (t < 256) {
        float wsh = wi_l[t] * s0 + wi_l[t + 1] * s1 + wi_l[t + 2] * s2;
        float pv = powf(wsh, gamma);
        pl[t] = pv;
        ps = pv;
    }
    ps = wave_sum(ps);
    if (t < 256 && lane == 0) s_ps[wv] = ps;
    __syncthreads();
    if (t == 0) ws[WS_PSUM + b] = s_ps[0] + s_ps[1] + s_ps[2] + s_ps[3];

    // --- partial column sums: each thread 32 rows (stride 8) of float4 ---
    const int col = (t & 127) * 4;
    const int rq = t >> 7;  // [0,8)
    float4 acc = make_float4(0.f, 0.f, 0.f, 0.f);
    const float* basep = mem + (size_t)start * 512 + col;
    #pragma unroll 8
    for (int r = rq; r < 256; r += 8) {
        float w = pl[r];
        float4 v = ld4(basep + (size_t)r * 512);
        acc.x += w * v.x; acc.y += w * v.y; acc.z += w * v.z; acc.w += w * v.w;
    }
    if (rq > 0) sacc[rq - 1][t & 127] = acc;
    __syncthreads();
    if (rq == 0) {
        #pragma unroll
        for (int i = 0; i < 7; ++i) {
            float4 a1 = sacc[i][t & 127];
            acc.x += a1.x; acc.y += a1.y; acc.z += a1.z; acc.w += a1.w;
        }
        *(float4*)(ws + WS_PART + (size_t)b * 512 + col) = acc;
    }
}

// K5: fused final reduce + output. 64 blocks x 256 threads (wave per output).
__global__ __launch_bounds__(256) void k_out(const float* __restrict__ W_out,
                                             const float* __restrict__ b_out,
                                             const float* __restrict__ ws,
                                             float* __restrict__ out) {
    const int t = threadIdx.x, lane = t & 63, wv = t >> 6;
    __shared__ float rd[512];
    __shared__ float s_z[4];
    float z = (t < 256) ? ws[WS_PSUM + t] : 0.f;
    z = wave_sum(z);
    if (lane == 0) s_z[wv] = z;
    float2 acc = make_float2(0.f, 0.f);
    const float* pp = ws + WS_PART + t * 2;
    #pragma unroll 16
    for (int r = 0; r < 256; ++r) {
        float2 v = *(const float2*)(pp + (size_t)r * 512);
        acc.x += v.x; acc.y += v.y;
    }
    __syncthreads();
    const float Zp = s_z[0] + s_z[1] + s_z[2] + s_z[3];
    const float invZp = 1.f / (Zp + EPS);
    rd[2 * t] = acc.x * invZp;
    rd[2 * t + 1] = acc.y * invZp;
    __syncthreads();
    const int o = blockIdx.x * 4 + wv;
    const float* wo = W_out + (size_t)o * 1024;
    float a = dot4(ld4(wo + lane * 4), ld4(ws + WS_HNEW + lane * 4))
            + dot4(ld4(wo + 256 + lane * 4), ld4(ws + WS_HNEW + 256 + lane * 4))
            + dot4(ld4(wo + 512 + lane * 4), ld4(rd + lane * 4))
            + dot4(ld4(wo + 768 + lane * 4), ld4(rd + 256 + lane * 4));
    a = wave_sum(a);
    if (lane == 0) out[o] = sigm(a + b_out[o]);
}

extern "C" void kernel_launch(void* const* d_in, const int* in_sizes, int n_in,
                              void* d_out, int out_size, void* d_ws, size_t ws_size,
                              hipStream_t stream) {
    const float* x          = (const float*)d_in[0];
    const float* memory     = (const float*)d_in[1];
    const float* prev_read  = (const float*)d_in[2];
    const float* h          = (const float*)d_in[3];
    const float* c          = (const float*)d_in[4];
    const float* read_state = (const float*)d_in[5];
    // d_in[6] write_state, d_in[13] W_write, d_in[14] b_write: dead in reference
    const float* W_ih   = (const float*)d_in[7];
    const float* b_ih   = (const float*)d_in[8];
    const float* W_hh   = (const float*)d_in[9];
    const float* b_hh   = (const float*)d_in[10];
    const float* W_read = (const float*)d_in[11];
    const float* b_read = (const float*)d_in[12];
    const float* W_out  = (const float*)d_in[15];
    const float* b_out  = (const float*)d_in[16];
    float* ws  = (float*)d_ws;
    float* out = (float*)d_out;

    k_gates<<<512, 256, 0, stream>>>(x, prev_read, h, W_ih, b_ih, W_hh, b_hh, ws);
    k_hr<<<130, 256, 0, stream>>>(c, W_read, b_read, ws);
    k_cos<<<2048, 256, 0, stream>>>(memory, ws);
    k_read<<<256, 1024, 0, stream>>>(memory, read_state, ws);
    k_out<<<64, 256, 0, stream>>>(W_out, b_out, ws, out);
}

// Round 8
// 77.902 us; speedup vs baseline: 4.4584x; 1.0360x over previous
//
#include <hip/hip_runtime.h>
#include <math.h>

#define EPS 1e-8f
#define NN 65536
#define MAGIC 1.0f

// ws float offsets
#define WS_GATES 0       // 2048
#define WS_HNEW  2048    // 512
#define WS_ROUT  2560    // 518 (pad 520)
#define WS_PMAX  3104    // 2048
#define WS_PEXP  5152    // 2048
#define WS_S     7200    // 65536
#define WS_PSUM  72736   // 256
#define WS_PART  72992   // 256*512 = 131072
#define WS_FLAGG 204064  // 128 gate-block flags
#define WS_FLAGP 204192  // 256 part-block flags

__device__ __forceinline__ float wave_sum(float v) {
    for (int o = 32; o > 0; o >>= 1) v += __shfl_xor(v, o);
    return v;
}
__device__ __forceinline__ float sigm(float x) { return 1.f / (1.f + expf(-x)); }
__device__ __forceinline__ float softplusf_(float x) {
    return x > 20.f ? x : log1pf(expf(x));
}
__device__ __forceinline__ float dot4(float4 a, float4 b) {
    return a.x * b.x + a.y * b.y + a.z * b.z + a.w * b.w;
}
__device__ __forceinline__ float4 ld4(const float* p) { return *(const float4*)p; }

// agent-scope coherent accessors (R6-proven on this chip)
__device__ __forceinline__ float ald(const float* p) {
    return __hip_atomic_load(p, __ATOMIC_RELAXED, __HIP_MEMORY_SCOPE_AGENT);
}
__device__ __forceinline__ float ald_acq(const float* p) {
    return __hip_atomic_load(p, __ATOMIC_ACQUIRE, __HIP_MEMORY_SCOPE_AGENT);
}
__device__ __forceinline__ void ast(float* p, float v) {
    __hip_atomic_store(p, v, __ATOMIC_RELAXED, __HIP_MEMORY_SCOPE_AGENT);
}
__device__ __forceinline__ void ast_rel(float* p, float v) {
    __hip_atomic_store(p, v, __ATOMIC_RELEASE, __HIP_MEMORY_SCOPE_AGENT);
}
__device__ __forceinline__ float2 ald2(const float* p) {
    unsigned long long u = __hip_atomic_load((const unsigned long long*)p,
        __ATOMIC_RELAXED, __HIP_MEMORY_SCOPE_AGENT);
    float2 r; __builtin_memcpy(&r, &u, 8); return r;
}
__device__ __forceinline__ void ast2(float* p, float2 v) {
    unsigned long long u; __builtin_memcpy(&u, &v, 8);
    __hip_atomic_store((unsigned long long*)p, u,
        __ATOMIC_RELAXED, __HIP_MEMORY_SCOPE_AGENT);
}

// K1: gates (blocks 0-127, 16 rows each) -> per-block flag -> h_new + r_out
// 130 blocks x 256 threads
__global__ __launch_bounds__(256) void k_front(const float* __restrict__ x,
                                               const float* __restrict__ pr,
                                               const float* __restrict__ h,
                                               const float* __restrict__ c,
                                               const float* __restrict__ W_ih,
                                               const float* __restrict__ b_ih,
                                               const float* __restrict__ W_hh,
                                               const float* __restrict__ b_hh,
                                               const float* __restrict__ W_read,
                                               const float* __restrict__ b_read,
                                               float* __restrict__ ws) {
    const int b = blockIdx.x, t = threadIdx.x;
    const int lane = t & 63, wv = t >> 6;
    __shared__ float sh[512];

    // ---- phase A: gates rows [b*16, b*16+16), 4 per wave ----
    if (b < 128) {
        #pragma unroll
        for (int i = 0; i < 4; ++i) {
            const int row = b * 16 + wv * 4 + i;
            const float* wi = W_ih + (size_t)row * 768;
            const float* wh = W_hh + (size_t)row * 512;
            float acc = dot4(ld4(wi + lane * 4), ld4(x + lane * 4))
                      + dot4(ld4(wi + 256 + lane * 4), ld4(pr + lane * 4))
                      + dot4(ld4(wi + 512 + lane * 4), ld4(pr + 256 + lane * 4))
                      + dot4(ld4(wh + lane * 4), ld4(h + lane * 4))
                      + dot4(ld4(wh + 256 + lane * 4), ld4(h + 256 + lane * 4));
            acc = wave_sum(acc);
            if (lane == 0) ast(ws + WS_GATES + row, acc + b_ih[row] + b_hh[row]);
        }
        __syncthreads();
        if (t == 0) ast_rel(ws + WS_FLAGG + b, MAGIC);
    }

    // ---- wait for all 128 gate flags (wave 0 polls; no same-line RMW) ----
    if (wv == 0) {
        int cap = 0;
        for (;;) {
            float v0 = ald_acq(ws + WS_FLAGG + lane);
            float v1 = ald_acq(ws + WS_FLAGG + 64 + lane);
            if (__all(v0 == MAGIC && v1 == MAGIC)) break;
            __builtin_amdgcn_s_sleep(1);
            if (++cap > (1 << 20)) break;  // fail loud, not hang
        }
    }
    __syncthreads();

    // ---- phase B: h_new (redundant per block) + r_out ----
    for (int j = t; j < 512; j += 256) {
        float ig = ald(ws + WS_GATES + j);
        float fg = ald(ws + WS_GATES + 512 + j);
        float gg = ald(ws + WS_GATES + 1024 + j);
        float og = ald(ws + WS_GATES + 1536 + j);
        float cn = sigm(fg) * c[j] + sigm(ig) * tanhf(gg);
        float hn = sigm(og) * tanhf(cn);
        sh[j] = hn;
        if (b == 0) ws[WS_HNEW + j] = hn;  // cross-kernel consumer
    }
    __syncthreads();
    const int o = b * 4 + wv;
    if (o < 518) {
        const float* wr = W_read + (size_t)o * 512;
        float acc = dot4(ld4(wr + lane * 4), ld4(sh + lane * 4))
                  + dot4(ld4(wr + 256 + lane * 4), ld4(sh + 256 + lane * 4));
        acc = wave_sum(acc);
        if (lane == 0) ws[WS_ROUT + o] = acc + b_read[o];
    }
}

// K2: s[n] = beta*cos(mem[n]+eps, key+eps); per-block online (max, expsum)
__global__ __launch_bounds__(256) void k_cos(const float* __restrict__ mem,
                                             float* __restrict__ ws) {
    const int t = threadIdx.x, lane = t & 63, wv = t >> 6;
    const int gw = blockIdx.x * 4 + wv;
    const float* key = ws + WS_ROUT;
    float4 ka = ld4(key + lane * 4);
    float4 kb = ld4(key + 256 + lane * 4);
    ka.x += EPS; ka.y += EPS; ka.z += EPS; ka.w += EPS;
    kb.x += EPS; kb.y += EPS; kb.z += EPS; kb.w += EPS;
    float kq = wave_sum(dot4(ka, ka) + dot4(kb, kb));
    const float nb = fmaxf(sqrtf(kq), EPS);
    const float beta = softplusf_(key[512]);
    float* sp = ws + WS_S;
    float m = -1e30f, e = 0.f;
    for (int n = gw; n < NN; n += 8192) {
        float4 va = ld4(mem + (size_t)n * 512 + lane * 4);
        float4 vb = ld4(mem + (size_t)n * 512 + 256 + lane * 4);
        va.x += EPS; va.y += EPS; va.z += EPS; va.w += EPS;
        vb.x += EPS; vb.y += EPS; vb.z += EPS; vb.w += EPS;
        float dot = wave_sum(dot4(va, ka) + dot4(vb, kb));
        float sq  = wave_sum(dot4(va, va) + dot4(vb, vb));
        float na = fmaxf(sqrtf(sq), EPS);
        float sv = beta * dot / (na * nb);
        if (lane == 0) sp[n] = sv;
        float nm = fmaxf(m, sv);
        e = e * expf(m - nm) + expf(sv - nm);
        m = nm;
    }
    __shared__ float sm[4], se[4];
    if (lane == 0) { sm[wv] = m; se[wv] = e; }
    __syncthreads();
    if (t == 0) {
        float M = fmaxf(fmaxf(sm[0], sm[1]), fmaxf(sm[2], sm[3]));
        float E = se[0] * expf(sm[0] - M) + se[1] * expf(sm[1] - M) +
                  se[2] * expf(sm[2] - M) + se[3] * expf(sm[3] - M);
        ws[WS_PMAX + blockIdx.x] = M;
        ws[WS_PEXP + blockIdx.x] = E;
    }
}

// K3: stats + p + partial column sums (256 blocks x 512 thr, R3-proven) ->
//     per-block flag -> blocks 0..31 poll and do the output phase.
__global__ __launch_bounds__(512) void k_readout(const float* __restrict__ mem,
                                                 const float* __restrict__ rs,
                                                 const float* __restrict__ W_out,
                                                 const float* __restrict__ b_out,
                                                 float* __restrict__ ws,
                                                 float* __restrict__ out) {
    const int b = blockIdx.x, t = threadIdx.x;
    const int lane = t & 63, wv = t >> 6;
    __shared__ float s_m[8], s_e[8];
    __shared__ float wi_l[258];
    __shared__ float pl[256];
    __shared__ float s_ps[4];
    __shared__ float4 sacc[3][128];
    __shared__ float rd[512];
    __shared__ float s_z[8];

    // --- redundant global softmax stats from 2048 (max, expsum) partials ---
    float m = -1e30f, e = 0.f;
    for (int i = t; i < 2048; i += 512) {
        float bm = ws[WS_PMAX + i], be = ws[WS_PEXP + i];
        float nm = fmaxf(m, bm);
        e = e * expf(m - nm) + be * expf(bm - nm);
        m = nm;
    }
    for (int o = 32; o > 0; o >>= 1) {
        float om = __shfl_xor(m, o), oe = __shfl_xor(e, o);
        float nm = fmaxf(m, om);
        e = e * expf(m - nm) + oe * expf(om - nm);
        m = nm;
    }
    if (lane == 0) { s_m[wv] = m; s_e[wv] = e; }
    __syncthreads();
    float mx = s_m[0];
    for (int i = 1; i < 8; ++i) mx = fmaxf(mx, s_m[i]);
    float Z = 0.f;
    for (int i = 0; i < 8; ++i) Z += s_e[i] * expf(s_m[i] - mx);
    const float invZ = 1.f / Z;
    const float g = sigm(ws[WS_ROUT + 513]);
    float a3 = ws[WS_ROUT + 514], b3 = ws[WS_ROUT + 515], c3 = ws[WS_ROUT + 516];
    float mm = fmaxf(a3, fmaxf(b3, c3));
    float ea = expf(a3 - mm), eb = expf(b3 - mm), ec = expf(c3 - mm);
    float ss = ea + eb + ec;
    const float s0 = ea / ss, s1 = eb / ss, s2 = ec / ss;
    const float gamma = 1.f + softplusf_(ws[WS_ROUT + 517]);

    // --- p for rows [b*256, b*256+256) ---
    const int start = b * 256;
    const float* sp = ws + WS_S;
    if (t < 258) {
        int idx = (start - 1 + t) & (NN - 1);
        wi_l[t] = g * rs[idx] + (1.f - g) * expf(sp[idx] - mx) * invZ;
    }
    __syncthreads();
    float ps = 0.f;
    if (t < 256) {
        float wsh = wi_l[t] * s0 + wi_l[t + 1] * s1 + wi_l[t + 2] * s2;
        float pv = powf(wsh, gamma);
        pl[t] = pv;
        ps = pv;
    }
    ps = wave_sum(ps);
    if (t < 256 && lane == 0) s_ps[wv] = ps;
    __syncthreads();
    if (t == 0) ast(ws + WS_PSUM + b, s_ps[0] + s_ps[1] + s_ps[2] + s_ps[3]);

    // --- partial column sums: thread (col4=(t&127)*4, rq=t>>7 in [0,4)) ---
    const int col = (t & 127) * 4;
    const int rq = t >> 7;
    float4 acc = make_float4(0.f, 0.f, 0.f, 0.f);
    const float* basep = mem + (size_t)start * 512 + col;
    #pragma unroll 8
    for (int r = rq; r < 256; r += 4) {
        float w = pl[r];
        float4 v = ld4(basep + (size_t)r * 512);
        acc.x += w * v.x; acc.y += w * v.y; acc.z += w * v.z; acc.w += w * v.w;
    }
    if (rq > 0) sacc[rq - 1][t & 127] = acc;
    __syncthreads();
    if (rq == 0) {
        float4 a0 = sacc[0][t & 127], a1 = sacc[1][t & 127], a2 = sacc[2][t & 127];
        acc.x += a0.x + a1.x + a2.x;
        acc.y += a0.y + a1.y + a2.y;
        acc.z += a0.z + a1.z + a2.z;
        acc.w += a0.w + a1.w + a2.w;
        float* pp = ws + WS_PART + (size_t)b * 512 + col;
        ast2(pp, make_float2(acc.x, acc.y));
        ast2(pp + 2, make_float2(acc.z, acc.w));
    }
    __syncthreads();
    if (t == 0) ast_rel(ws + WS_FLAGP + b, MAGIC);

    // ================= output phase: blocks 0..31 =================
    if (b >= 32) return;
    if (wv == 0) {
        int cap = 0;
        for (;;) {
            float v0 = ald_acq(ws + WS_FLAGP + lane);
            float v1 = ald_acq(ws + WS_FLAGP + 64 + lane);
            float v2 = ald_acq(ws + WS_FLAGP + 128 + lane);
            float v3 = ald_acq(ws + WS_FLAGP + 192 + lane);
            if (__all(v0 == MAGIC && v1 == MAGIC && v2 == MAGIC && v3 == MAGIC))
                break;
            __builtin_amdgcn_s_sleep(1);
            if (++cap > (1 << 20)) break;
        }
    }
    __syncthreads();
    // Zp
    float z = (t < 256) ? ald(ws + WS_PSUM + t) : 0.f;
    z = wave_sum(z);
    if (lane == 0) s_z[wv] = z;
    __syncthreads();
    float Zp = 0.f;
    for (int i = 0; i < 8; ++i) Zp += s_z[i];
    const float invZp = 1.f / (Zp + EPS);
    // rd: threads 0..255 sweep PART columns
    if (t < 256) {
        float ax = 0.f, ay = 0.f;
        const float* pp = ws + WS_PART + t * 2;
        #pragma unroll 16
        for (int r = 0; r < 256; ++r) {
            float2 v = ald2(pp + (size_t)r * 512);
            ax += v.x; ay += v.y;
        }
        rd[2 * t] = ax * invZp;
        rd[2 * t + 1] = ay * invZp;
    }
    __syncthreads();
    // out: wave per output, o = b*8 + wv  (32 blocks x 8 waves = 256)
    const int o = b * 8 + wv;
    const float* wo = W_out + (size_t)o * 1024;
    float a = dot4(ld4(wo + lane * 4), ld4(ws + WS_HNEW + lane * 4))
            + dot4(ld4(wo + 256 + lane * 4), ld4(ws + WS_HNEW + 256 + lane * 4))
            + dot4(ld4(wo + 512 + lane * 4), ld4(rd + lane * 4))
            + dot4(ld4(wo + 768 + lane * 4), ld4(rd + 256 + lane * 4));
    a = wave_sum(a);
    if (lane == 0) out[o] = sigm(a + b_out[o]);
}

extern "C" void kernel_launch(void* const* d_in, const int* in_sizes, int n_in,
                              void* d_out, int out_size, void* d_ws, size_t ws_size,
                              hipStream_t stream) {
    const float* x          = (const float*)d_in[0];
    const float* memory     = (const float*)d_in[1];
    const float* prev_read  = (const float*)d_in[2];
    const float* h          = (const float*)d_in[3];
    const float* c          = (const float*)d_in[4];
    const float* read_state = (const float*)d_in[5];
    // d_in[6] write_state, d_in[13] W_write, d_in[14] b_write: dead in reference
    const float* W_ih   = (const float*)d_in[7];
    const float* b_ih   = (const float*)d_in[8];
    const float* W_hh   = (const float*)d_in[9];
    const float* b_hh   = (const float*)d_in[10];
    const float* W_read = (const float*)d_in[11];
    const float* b_read = (const float*)d_in[12];
    const float* W_out  = (const float*)d_in[15];
    const float* b_out  = (const float*)d_in[16];
    float* ws  = (float*)d_ws;
    float* out = (float*)d_out;

    k_front<<<130, 256, 0, stream>>>(x, prev_read, h, c, W_ih, b_ih, W_hh, b_hh,
                                     W_read, b_read, ws);
    k_cos<<<2048, 256, 0, stream>>>(memory, ws);
    k_readout<<<256, 512, 0, stream>>>(memory, read_state, W_out, b_out, ws, out);
}

// Round 9
// 76.583 us; speedup vs baseline: 4.5352x; 1.0172x over previous
//
#include <hip/hip_runtime.h>
#include <math.h>

#define EPS 1e-8f
#define NN 65536
#define MAGIC 1.0f

// ws float offsets
#define WS_GATES 0       // 2048
#define WS_HNEW  2048    // 512
#define WS_ROUT  2560    // 518 (pad 520)
#define WS_PMAX  3104    // 2048
#define WS_PEXP  5152    // 2048
#define WS_S     7200    // 65536
#define WS_PSUM  72736   // 256
#define WS_PART  72992   // 256*512 = 131072
#define WS_FLAGG 204064  // 128 gate-block flags
#define WS_FLAGP 204192  // 256 part-block flags
#define WS_BF    262144  // bf16 shadow of memory: 65536*512*2B = 64 MB (as shorts)

__device__ __forceinline__ float wave_sum(float v) {
    for (int o = 32; o > 0; o >>= 1) v += __shfl_xor(v, o);
    return v;
}
__device__ __forceinline__ float sigm(float x) { return 1.f / (1.f + expf(-x)); }
__device__ __forceinline__ float softplusf_(float x) {
    return x > 20.f ? x : log1pf(expf(x));
}
__device__ __forceinline__ float dot4(float4 a, float4 b) {
    return a.x * b.x + a.y * b.y + a.z * b.z + a.w * b.w;
}
__device__ __forceinline__ float4 ld4(const float* p) { return *(const float4*)p; }

// agent-scope coherent accessors (R6/R8-proven on this chip)
__device__ __forceinline__ float ald(const float* p) {
    return __hip_atomic_load(p, __ATOMIC_RELAXED, __HIP_MEMORY_SCOPE_AGENT);
}
__device__ __forceinline__ float ald_acq(const float* p) {
    return __hip_atomic_load(p, __ATOMIC_ACQUIRE, __HIP_MEMORY_SCOPE_AGENT);
}
__device__ __forceinline__ void ast(float* p, float v) {
    __hip_atomic_store(p, v, __ATOMIC_RELAXED, __HIP_MEMORY_SCOPE_AGENT);
}
__device__ __forceinline__ void ast_rel(float* p, float v) {
    __hip_atomic_store(p, v, __ATOMIC_RELEASE, __HIP_MEMORY_SCOPE_AGENT);
}
__device__ __forceinline__ float2 ald2(const float* p) {
    unsigned long long u = __hip_atomic_load((const unsigned long long*)p,
        __ATOMIC_RELAXED, __HIP_MEMORY_SCOPE_AGENT);
    float2 r; __builtin_memcpy(&r, &u, 8); return r;
}
__device__ __forceinline__ void ast2(float* p, float2 v) {
    unsigned long long u; __builtin_memcpy(&u, &v, 8);
    __hip_atomic_store((unsigned long long*)p, u,
        __ATOMIC_RELAXED, __HIP_MEMORY_SCOPE_AGENT);
}

// pack two floats as RNE bf16 into one uint (a low short, b high short)
__device__ __forceinline__ unsigned bf2(float a, float b) {
    unsigned ua = __float_as_uint(a), ub = __float_as_uint(b);
    unsigned ra = (ua + 0x7FFFu + ((ua >> 16) & 1u)) >> 16;
    unsigned rb = (ub + 0x7FFFu + ((ub >> 16) & 1u)) >> 16;
    return ra | (rb << 16);
}

// K1: gates (blocks 0-127, 16 rows each) -> per-block flag -> h_new + r_out
__global__ __launch_bounds__(256) void k_front(const float* __restrict__ x,
                                               const float* __restrict__ pr,
                                               const float* __restrict__ h,
                                               const float* __restrict__ c,
                                               const float* __restrict__ W_ih,
                                               const float* __restrict__ b_ih,
                                               const float* __restrict__ W_hh,
                                               const float* __restrict__ b_hh,
                                               const float* __restrict__ W_read,
                                               const float* __restrict__ b_read,
                                               float* __restrict__ ws) {
    const int b = blockIdx.x, t = threadIdx.x;
    const int lane = t & 63, wv = t >> 6;
    __shared__ float sh[512];

    if (b < 128) {
        #pragma unroll
        for (int i = 0; i < 4; ++i) {
            const int row = b * 16 + wv * 4 + i;
            const float* wi = W_ih + (size_t)row * 768;
            const float* wh = W_hh + (size_t)row * 512;
            float acc = dot4(ld4(wi + lane * 4), ld4(x + lane * 4))
                      + dot4(ld4(wi + 256 + lane * 4), ld4(pr + lane * 4))
                      + dot4(ld4(wi + 512 + lane * 4), ld4(pr + 256 + lane * 4))
                      + dot4(ld4(wh + lane * 4), ld4(h + lane * 4))
                      + dot4(ld4(wh + 256 + lane * 4), ld4(h + 256 + lane * 4));
            acc = wave_sum(acc);
            if (lane == 0) ast(ws + WS_GATES + row, acc + b_ih[row] + b_hh[row]);
        }
        __syncthreads();
        if (t == 0) ast_rel(ws + WS_FLAGG + b, MAGIC);
    }

    if (wv == 0) {
        int cap = 0;
        for (;;) {
            float v0 = ald_acq(ws + WS_FLAGG + lane);
            float v1 = ald_acq(ws + WS_FLAGG + 64 + lane);
            if (__all(v0 == MAGIC && v1 == MAGIC)) break;
            __builtin_amdgcn_s_sleep(1);
            if (++cap > (1 << 20)) break;
        }
    }
    __syncthreads();

    for (int j = t; j < 512; j += 256) {
        float ig = ald(ws + WS_GATES + j);
        float fg = ald(ws + WS_GATES + 512 + j);
        float gg = ald(ws + WS_GATES + 1024 + j);
        float og = ald(ws + WS_GATES + 1536 + j);
        float cn = sigm(fg) * c[j] + sigm(ig) * tanhf(gg);
        float hn = sigm(og) * tanhf(cn);
        sh[j] = hn;
        if (b == 0) ws[WS_HNEW + j] = hn;
    }
    __syncthreads();
    const int o = b * 4 + wv;
    if (o < 518) {
        const float* wr = W_read + (size_t)o * 512;
        float acc = dot4(ld4(wr + lane * 4), ld4(sh + lane * 4))
                  + dot4(ld4(wr + 256 + lane * 4), ld4(sh + 256 + lane * 4));
        acc = wave_sum(acc);
        if (lane == 0) ws[WS_ROUT + o] = acc + b_read[o];
    }
}

// K2: cosine scores + bf16 shadow write (row already in registers)
__global__ __launch_bounds__(256) void k_cos(const float* __restrict__ mem,
                                             float* __restrict__ ws) {
    const int t = threadIdx.x, lane = t & 63, wv = t >> 6;
    const int gw = blockIdx.x * 4 + wv;
    const float* key = ws + WS_ROUT;
    unsigned short* wsb = (unsigned short*)(ws + WS_BF);
    float4 ka = ld4(key + lane * 4);
    float4 kb = ld4(key + 256 + lane * 4);
    ka.x += EPS; ka.y += EPS; ka.z += EPS; ka.w += EPS;
    kb.x += EPS; kb.y += EPS; kb.z += EPS; kb.w += EPS;
    float kq = wave_sum(dot4(ka, ka) + dot4(kb, kb));
    const float nb = fmaxf(sqrtf(kq), EPS);
    const float beta = softplusf_(key[512]);
    float* sp = ws + WS_S;
    float m = -1e30f, e = 0.f;
    for (int n = gw; n < NN; n += 8192) {
        float4 va = ld4(mem + (size_t)n * 512 + lane * 4);
        float4 vb = ld4(mem + (size_t)n * 512 + 256 + lane * 4);
        // bf16 shadow of the RAW row (before EPS)
        uint2 p0 = make_uint2(bf2(va.x, va.y), bf2(va.z, va.w));
        uint2 p1 = make_uint2(bf2(vb.x, vb.y), bf2(vb.z, vb.w));
        *(uint2*)(wsb + (size_t)n * 512 + lane * 4) = p0;
        *(uint2*)(wsb + (size_t)n * 512 + 256 + lane * 4) = p1;
        va.x += EPS; va.y += EPS; va.z += EPS; va.w += EPS;
        vb.x += EPS; vb.y += EPS; vb.z += EPS; vb.w += EPS;
        float dot = dot4(va, ka) + dot4(vb, kb);
        float sq  = dot4(va, va) + dot4(vb, vb);
        for (int o = 32; o > 0; o >>= 1) {
            dot += __shfl_xor(dot, o);
            sq  += __shfl_xor(sq, o);
        }
        float na = fmaxf(sqrtf(sq), EPS);
        float sv = beta * dot / (na * nb);
        if (lane == 0) sp[n] = sv;
        float nm = fmaxf(m, sv);
        e = e * expf(m - nm) + expf(sv - nm);
        m = nm;
    }
    __shared__ float sm[4], se[4];
    if (lane == 0) { sm[wv] = m; se[wv] = e; }
    __syncthreads();
    if (t == 0) {
        float M = fmaxf(fmaxf(sm[0], sm[1]), fmaxf(sm[2], sm[3]));
        float E = se[0] * expf(sm[0] - M) + se[1] * expf(sm[1] - M) +
                  se[2] * expf(sm[2] - M) + se[3] * expf(sm[3] - M);
        ws[WS_PMAX + blockIdx.x] = M;
        ws[WS_PEXP + blockIdx.x] = E;
    }
}

// K3: stats + p + bf16 partial column sums -> flag -> blocks 0..31 output phase
__global__ __launch_bounds__(512) void k_readout(const float* __restrict__ rs,
                                                 const float* __restrict__ W_out,
                                                 const float* __restrict__ b_out,
                                                 float* __restrict__ ws,
                                                 float* __restrict__ out) {
    const int b = blockIdx.x, t = threadIdx.x;
    const int lane = t & 63, wv = t >> 6;
    __shared__ float s_m[8], s_e[8];
    __shared__ float wi_l[258];
    __shared__ float pl[256];
    __shared__ float s_ps[4];
    __shared__ float sacc[8][512];   // 16 KB cross-wave reduce
    __shared__ float rd[512];
    __shared__ float s_z[8];

    // --- global softmax stats from 2048 (max, expsum) partials ---
    float m = -1e30f, e = 0.f;
    for (int i = t; i < 2048; i += 512) {
        float bm = ws[WS_PMAX + i], be = ws[WS_PEXP + i];
        float nm = fmaxf(m, bm);
        e = e * expf(m - nm) + be * expf(bm - nm);
        m = nm;
    }
    for (int o = 32; o > 0; o >>= 1) {
        float om = __shfl_xor(m, o), oe = __shfl_xor(e, o);
        float nm = fmaxf(m, om);
        e = e * expf(m - nm) + oe * expf(om - nm);
        m = nm;
    }
    if (lane == 0) { s_m[wv] = m; s_e[wv] = e; }
    __syncthreads();
    float mx = s_m[0];
    for (int i = 1; i < 8; ++i) mx = fmaxf(mx, s_m[i]);
    float Z = 0.f;
    for (int i = 0; i < 8; ++i) Z += s_e[i] * expf(s_m[i] - mx);
    const float invZ = 1.f / Z;
    const float g = sigm(ws[WS_ROUT + 513]);
    float a3 = ws[WS_ROUT + 514], b3 = ws[WS_ROUT + 515], c3 = ws[WS_ROUT + 516];
    float mm = fmaxf(a3, fmaxf(b3, c3));
    float ea = expf(a3 - mm), eb = expf(b3 - mm), ec = expf(c3 - mm);
    float ss = ea + eb + ec;
    const float s0 = ea / ss, s1 = eb / ss, s2 = ec / ss;
    const float gamma = 1.f + softplusf_(ws[WS_ROUT + 517]);

    // --- p for rows [b*256, b*256+256) ---
    const int start = b * 256;
    const float* sp = ws + WS_S;
    if (t < 258) {
        int idx = (start - 1 + t) & (NN - 1);
        wi_l[t] = g * rs[idx] + (1.f - g) * expf(sp[idx] - mx) * invZ;
    }
    __syncthreads();
    float ps = 0.f;
    if (t < 256) {
        float wsh = wi_l[t] * s0 + wi_l[t + 1] * s1 + wi_l[t + 2] * s2;
        float pv = powf(wsh, gamma);
        pl[t] = pv;
        ps = pv;
    }
    ps = wave_sum(ps);
    if (t < 256 && lane == 0) s_ps[wv] = ps;
    __syncthreads();
    if (t == 0) ast(ws + WS_PSUM + b, s_ps[0] + s_ps[1] + s_ps[2] + s_ps[3]);

    // --- bf16 partial column sums: wave wv sweeps rows wv, wv+8, ... (32 rows);
    //     lane covers 8 contiguous cols via one uint4 (16B) load per row ---
    {
        const unsigned short* wsb = (const unsigned short*)(ws + WS_BF);
        float a0 = 0.f, a1 = 0.f, a2 = 0.f, a3f = 0.f,
              a4 = 0.f, a5 = 0.f, a6 = 0.f, a7 = 0.f;
        #pragma unroll 4
        for (int r = wv; r < 256; r += 8) {
            float w = pl[r];
            uint4 q = *(const uint4*)(wsb + (size_t)(start + r) * 512 + lane * 8);
            a0 += w * __uint_as_float(q.x << 16);
            a1 += w * __uint_as_float(q.x & 0xFFFF0000u);
            a2 += w * __uint_as_float(q.y << 16);
            a3f += w * __uint_as_float(q.y & 0xFFFF0000u);
            a4 += w * __uint_as_float(q.z << 16);
            a5 += w * __uint_as_float(q.z & 0xFFFF0000u);
            a6 += w * __uint_as_float(q.w << 16);
            a7 += w * __uint_as_float(q.w & 0xFFFF0000u);
        }
        float* sw = &sacc[wv][lane * 8];
        sw[0] = a0; sw[1] = a1; sw[2] = a2; sw[3] = a3f;
        sw[4] = a4; sw[5] = a5; sw[6] = a6; sw[7] = a7;
    }
    __syncthreads();
    if (t < 256) {
        const int cc = t * 2;
        float u0 = 0.f, u1 = 0.f;
        #pragma unroll
        for (int w8 = 0; w8 < 8; ++w8) {
            u0 += sacc[w8][cc];
            u1 += sacc[w8][cc + 1];
        }
        ast2(ws + WS_PART + (size_t)b * 512 + cc, make_float2(u0, u1));
    }
    __syncthreads();
    if (t == 0) ast_rel(ws + WS_FLAGP + b, MAGIC);

    // ================= output phase: blocks 0..31 =================
    if (b >= 32) return;
    if (wv == 0) {
        int cap = 0;
        for (;;) {
            float v0 = ald_acq(ws + WS_FLAGP + lane);
            float v1 = ald_acq(ws + WS_FLAGP + 64 + lane);
            float v2 = ald_acq(ws + WS_FLAGP + 128 + lane);
            float v3 = ald_acq(ws + WS_FLAGP + 192 + lane);
            if (__all(v0 == MAGIC && v1 == MAGIC && v2 == MAGIC && v3 == MAGIC))
                break;
            __builtin_amdgcn_s_sleep(1);
            if (++cap > (1 << 20)) break;
        }
    }
    __syncthreads();
    float z = (t < 256) ? ald(ws + WS_PSUM + t) : 0.f;
    z = wave_sum(z);
    if (lane == 0) s_z[wv] = z;
    __syncthreads();
    float Zp = 0.f;
    for (int i = 0; i < 8; ++i) Zp += s_z[i];
    const float invZp = 1.f / (Zp + EPS);
    if (t < 256) {
        float ax = 0.f, ay = 0.f;
        const float* pp = ws + WS_PART + t * 2;
        #pragma unroll 16
        for (int r = 0; r < 256; ++r) {
            float2 v = ald2(pp + (size_t)r * 512);
            ax += v.x; ay += v.y;
        }
        rd[2 * t] = ax * invZp;
        rd[2 * t + 1] = ay * invZp;
    }
    __syncthreads();
    const int o = b * 8 + wv;
    const float* wo = W_out + (size_t)o * 1024;
    float a = dot4(ld4(wo + lane * 4), ld4(ws + WS_HNEW + lane * 4))
            + dot4(ld4(wo + 256 + lane * 4), ld4(ws + WS_HNEW + 256 + lane * 4))
            + dot4(ld4(wo + 512 + lane * 4), ld4(rd + lane * 4))
            + dot4(ld4(wo + 768 + lane * 4), ld4(rd + 256 + lane * 4));
    a = wave_sum(a);
    if (lane == 0) out[o] = sigm(a + b_out[o]);
}

extern "C" void kernel_launch(void* const* d_in, const int* in_sizes, int n_in,
                              void* d_out, int out_size, void* d_ws, size_t ws_size,
                              hipStream_t stream) {
    const float* x          = (const float*)d_in[0];
    const float* memory     = (const float*)d_in[1];
    const float* prev_read  = (const float*)d_in[2];
    const float* h          = (const float*)d_in[3];
    const float* c          = (const float*)d_in[4];
    const float* read_state = (const float*)d_in[5];
    // d_in[6] write_state, d_in[13] W_write, d_in[14] b_write: dead in reference
    const float* W_ih   = (const float*)d_in[7];
    const float* b_ih   = (const float*)d_in[8];
    const float* W_hh   = (const float*)d_in[9];
    const float* b_hh   = (const float*)d_in[10];
    const float* W_read = (const float*)d_in[11];
    const float* b_read = (const float*)d_in[12];
    const float* W_out  = (const float*)d_in[15];
    const float* b_out  = (const float*)d_in[16];
    float* ws  = (float*)d_ws;
    float* out = (float*)d_out;

    k_front<<<130, 256, 0, stream>>>(x, prev_read, h, c, W_ih, b_ih, W_hh, b_hh,
                                     W_read, b_read, ws);
    k_cos<<<2048, 256, 0, stream>>>(memory, ws);
    k_readout<<<256, 512, 0, stream>>>(read_state, W_out, b_out, ws, out);
}